// Round 7
// baseline (3735.278 us; speedup 1.0000x reference)
//
#include <hip/hip_runtime.h>
#include <hip/hip_bf16.h>
#include <math.h>

#define IDIM 128
#define HDIM 512
#define SDIM 64
#define BATCH 128
#define MAXT 259
#define G4 2048
#define KTOT 704    // 128 (x) + 64 (rt) + 512 (h)
#define ROUT 194    // 64 + 128 + 2
#define AFRAG_U 73728   // 8 mt * 18 ks * 64 lanes * 8 e (uints, hi|lo packed) per buffer
#define NBLK 256
#define NGATE 16    // gate blocks per group
#define PJ 224      // padded j-dim of part segment
#define PTJ 224     // pt row stride (14 j-tiles x 16)

typedef __hip_bfloat16 bf16;
typedef __attribute__((ext_vector_type(8))) short short8;
typedef __attribute__((ext_vector_type(4))) float floatx4;

__device__ __forceinline__ float sigmoidf_(float v) { return 1.f / (1.f + expf(-v)); }
__device__ __forceinline__ float b2f(bf16 v) { return __bfloat162float(v); }
__device__ __forceinline__ float load_in(const void* p, size_t i, int isf32) {
    return isf32 ? ((const float*)p)[i] : b2f(((const bf16*)p)[i]);
}
__device__ __forceinline__ unsigned short f2bfbits(float v) {
    unsigned u = __builtin_bit_cast(unsigned, v);
    unsigned r = (u + 0x7FFFu + ((u >> 16) & 1u)) >> 16;
    return (unsigned short)r;
}
__device__ __forceinline__ float bfbits2f(unsigned short b) {
    return __builtin_bit_cast(float, (unsigned)b << 16);
}
__device__ __forceinline__ unsigned aload(const unsigned* p) {
    return __hip_atomic_load(p, __ATOMIC_RELAXED, __HIP_MEMORY_SCOPE_AGENT);
}
__device__ __forceinline__ unsigned long long aload64(const unsigned long long* p) {
    return __hip_atomic_load(p, __ATOMIC_RELAXED, __HIP_MEMORY_SCOPE_AGENT);
}
__device__ __forceinline__ void astore64(unsigned long long* p, unsigned long long v) {
    __hip_atomic_store(p, v, __ATOMIC_RELAXED, __HIP_MEMORY_SCOPE_AGENT);
}
__device__ __forceinline__ unsigned long long packf2(float a, float b) {
    return (unsigned long long)__builtin_bit_cast(unsigned, a)
         | ((unsigned long long)__builtin_bit_cast(unsigned, b) << 32);
}
__device__ __forceinline__ void unpack_frag(const unsigned long long* ap,
                                            short8& ah, short8& al) {
    #pragma unroll
    for (int j = 0; j < 4; j++) {
        unsigned long long q = aload64(ap + j);
        unsigned u0 = (unsigned)q, u1 = (unsigned)(q >> 32);
        ah[2 * j]     = (short)(u0 & 0xffffu);
        al[2 * j]     = (short)(u0 >> 16);
        ah[2 * j + 1] = (short)(u1 & 0xffffu);
        al[2 * j + 1] = (short)(u1 >> 16);
    }
}

// Poll 16 consecutive epoch flags (stride-16 uints) until all >= tgt.
// Producers store flags AFTER a per-wave vmcnt drain of their data stores
// (+ __syncthreads across the block) -> flag >= tgt implies data visible.
__device__ __forceinline__ void wait_flags16(const unsigned* f, int base16,
                                             unsigned tgt) {
    if (threadIdx.x < 16) {
        while (aload(&f[(base16 + (int)threadIdx.x) * 16]) < tgt)
            __builtin_amdgcn_s_sleep(1);
    }
    __atomic_signal_fence(__ATOMIC_SEQ_CST);
    __syncthreads();
}

// dtype detect (defensive): f32 data has random low halves -> bf16-exp >= 0x8F
__global__ void detect_kernel(const unsigned short* __restrict__ w, int* __restrict__ flag) {
    if (threadIdx.x == 0) {
        int isf32 = 0;
        for (int i = 0; i < 256; i++) {
            int e = (w[i] >> 7) & 0xFF;
            if (e >= 0x8F) isf32 = 1;
        }
        *flag = isf32;
    }
}

// Gate-interleaved combined weights in B-fragment layout (hi/lo bf16 split).
__global__ void prep_kernel(const void* __restrict__ Wih, const void* __restrict__ bih,
                            const void* __restrict__ Whh, const void* __restrict__ bhh,
                            unsigned short* __restrict__ WfH, unsigned short* __restrict__ WfL,
                            float* __restrict__ bc, const int* __restrict__ flag) {
    int isf32 = *flag;
    int jp = blockIdx.x;
    int u = jp >> 2, gate = jp & 3;
    int src = gate * HDIM + u;
    int jt = jp >> 4, jn = jp & 15;
    for (int k = threadIdx.x; k < KTOT; k += blockDim.x) {
        float v = (k < 192) ? load_in(Wih, (size_t)src * 192 + k, isf32)
                            : load_in(Whh, (size_t)src * HDIM + (k - 192), isf32);
        unsigned short hi = f2bfbits(v);
        unsigned short lo = f2bfbits(v - bfbits2f(hi));
        int ks = k >> 5, q = (k & 31) >> 3, e = k & 7;
        size_t d = (((size_t)jt * 22 + ks) * 64 + (q * 16 + jn)) * 8 + e;
        WfH[d] = hi;
        WfL[d] = lo;
    }
    if (threadIdx.x == 0)
        bc[jp] = load_in(bih, src, isf32) + load_in(bhh, src, isf32);
}

// Wr -> row-major bf16 hi/lo (224 rows, rows >= 194 zero) + brf f32 (padded).
__global__ void wr_prep_kernel(const void* __restrict__ Wr, const void* __restrict__ br,
                               unsigned short* __restrict__ WrBh, unsigned short* __restrict__ WrBl,
                               float* __restrict__ brf, const int* __restrict__ flag) {
    int isf32 = *flag;
    int j = blockIdx.x;
    for (int k = threadIdx.x; k < HDIM; k += blockDim.x) {
        float v = (j < ROUT) ? load_in(Wr, (size_t)j * HDIM + k, isf32) : 0.f;
        unsigned short hi = f2bfbits(v);
        WrBh[(size_t)j * HDIM + k] = hi;
        WrBl[(size_t)j * HDIM + k] = f2bfbits(v - bfbits2f(hi));
    }
    if (threadIdx.x == 0) brf[j] = (j < ROUT) ? load_in(br, j, isf32) : 0.f;
}

// ------ persistent kernel (R18 = verified R15 + gate-local identity opts) ------
// Identical to R15 (3012us, passing) EXCEPT inside the gate block:
//   (a) A-frags are loaded DIRECT to registers via unpack_frag on the exact
//       addresses the R15 staging loop used (identity transform; removes the
//       Ahs/Als staging + 2 __syncthreads per step from the critical path);
//   (b) the x-MFMA section is hoisted BEFORE the hfl wait (x depends only on
//       global input), so its loads/MFMAs overlap the wait for h(t-1).
// P2 blocks, flags, readout-MFMA, part publish: R15 verbatim.
__global__ __launch_bounds__(256) void persist_kernel(
        const void* __restrict__ x,
        const unsigned short* __restrict__ WfH, const unsigned short* __restrict__ WfL,
        const float* __restrict__ bc,
        const unsigned short* __restrict__ WrBh, const unsigned short* __restrict__ WrBl,
        const float* __restrict__ brf,
        unsigned* __restrict__ AfP,          // 2 x AFRAG_U uints (hi | lo<<16)
        float* __restrict__ part,            // [128 rows][16 gb][PJ] f32
        unsigned short* __restrict__ Vg,     // [128][259][64] bf16, row-private
        void* __restrict__ dout, const int* __restrict__ flag,
        unsigned* __restrict__ hfl, unsigned* __restrict__ pfl,
        unsigned* __restrict__ rtf) {
    __shared__ __align__(16) float pt[16 * PTJ];                  // readout tile (14.3KB)
    __shared__ __align__(16) unsigned short wrslB[14 * 64 * 8];   // Wr hi, B-frag layout
    __shared__ __align__(16) unsigned short wrslBL[14 * 64 * 8];  // Wr lo, B-frag layout
    __shared__ __align__(16) float scr[8][16][20];
    __shared__ __align__(16) unsigned short hlh[16 * 40];     // h hi bf16 (pad 40)
    __shared__ __align__(16) unsigned short hll[16 * 40];     // h lo bf16
    __shared__ __align__(16) float outs[208];
    __shared__ __align__(16) float sL[324];
    __shared__ __align__(16) float aL[324];
    __shared__ __align__(16) float red[4][64];
    __shared__ __align__(16) float brS[208];
    __shared__ __align__(16) float bcS[128];
    __shared__ int e0S;

    const int tid = threadIdx.x, lane = tid & 63, wv = tid >> 6;
    const int blk = blockIdx.x, ms = blk >> 5, ns = blk & 31;
    const int isf32 = *flag;

    const int is_gate = (ns < 16);
    const int gb = ns;                   // gate block index (when is_gate)
    const int pb = ns - 16;              // P2 index (when !is_gate)
    const int p2row = ms * 16 + pb;      // P2's batch row

    if (is_gate) {
        // Wr slice in B-frag layout: tile jt (14), lane l, elem e ->
        // row j = jt*16 + (l&15), col k = gb*32 + (l>>4)*8 + e.
        for (int i = tid; i < 14 * 64 * 8; i += 256) {
            int jt = i >> 9, l = (i >> 3) & 63, e = i & 7;
            size_t src = (size_t)(jt * 16 + (l & 15)) * HDIM + gb * 32 + (l >> 4) * 8 + e;
            wrslB[i]  = WrBh[src];
            wrslBL[i] = WrBl[src];
        }
        if (tid < 128) bcS[tid] = bc[gb * 128 + tid];
    } else {
        for (int i = tid; i < 208; i += 256) brS[i] = brf[i];
        for (int i = tid; i < 324; i += 256) { sL[i] = 0.f; aL[i] = 0.f; }
    }
    __syncthreads();

    if (is_gate) {
        // =========================== GATE BLOCK ===========================
        const short8* WH = (const short8*)WfH;
        const short8* WL = (const short8*)WfL;
        const int jt0 = gb * 8 + wv, jt1 = gb * 8 + 4 + wv;
        const short8* wb0  = WH + (size_t)jt0 * 22 * 64;
        const short8* wb1  = WH + (size_t)jt1 * 22 * 64;
        const short8* wbl0 = WL + (size_t)jt0 * 22 * 64;
        const short8* wbl1 = WL + (size_t)jt1 * 22 * 64;
        float cc0 = 0.f, cc1 = 0.f;

        for (int t = 0; t < MAXT; t++) {
            const int cur = t & 1, nxt = cur ^ 1;
            const unsigned long long* AfPc64 =
                (const unsigned long long*)(AfP + (size_t)cur * AFRAG_U);
            unsigned long long* AfPn64 =
                (unsigned long long*)(AfP + (size_t)nxt * AFRAG_U);
            const int use_x = (t < 129);

            // P1-x: x MFMAs BEFORE the h wait (independent of h(t-1))
            floatx4 acc0 = {0.f, 0.f, 0.f, 0.f};
            floatx4 acc1 = {0.f, 0.f, 0.f, 0.f};
            if (use_x) {
                int m = lane & 15, q = lane >> 4;
                size_t xrow = ((size_t)t * BATCH + ms * 16 + m) * IDIM + q * 8;
                #pragma unroll
                for (int ks = 0; ks < 4; ks++) {
                    short8 a;
                    if (isf32) {
                        const float* xf = (const float*)x + xrow + ks * 32;
                        #pragma unroll
                        for (int i = 0; i < 8; i++) a[i] = (short)f2bfbits(xf[i]);
                    } else {
                        a = *(const short8*)((const unsigned short*)x + xrow + ks * 32);
                    }
                    acc0 = __builtin_amdgcn_mfma_f32_16x16x32_bf16(a, wb0[ks * 64 + lane], acc0, 0, 0, 0);
                    acc1 = __builtin_amdgcn_mfma_f32_16x16x32_bf16(a, wb1[ks * 64 + lane], acc1, 0, 0, 0);
                    if (isf32) {
                        acc0 = __builtin_amdgcn_mfma_f32_16x16x32_bf16(a, wbl0[ks * 64 + lane], acc0, 0, 0, 0);
                        acc1 = __builtin_amdgcn_mfma_f32_16x16x32_bf16(a, wbl1[ks * 64 + lane], acc1, 0, 0, 0);
                    }
                }
            }

            // wait h(t-1) frags, then h MFMAs with frags DIRECT to registers
            // (same addresses the R15 staging loop used: identity transform)
            wait_flags16(hfl, ms * 16, (unsigned)t);
            #pragma unroll 4
            for (int ksi = 2; ksi < 18; ksi++) {
                int ks = 4 + ksi;
                short8 ah, al8;
                unpack_frag(AfPc64 + ((size_t)(ms * 18 + ksi) * 64 + lane) * 4, ah, al8);
                short8 bh0 = wb0[ks * 64 + lane];
                short8 bh1 = wb1[ks * 64 + lane];
                acc0 = __builtin_amdgcn_mfma_f32_16x16x32_bf16(ah, bh0, acc0, 0, 0, 0);
                acc0 = __builtin_amdgcn_mfma_f32_16x16x32_bf16(al8, bh0, acc0, 0, 0, 0);
                acc1 = __builtin_amdgcn_mfma_f32_16x16x32_bf16(ah, bh1, acc1, 0, 0, 0);
                acc1 = __builtin_amdgcn_mfma_f32_16x16x32_bf16(al8, bh1, acc1, 0, 0, 0);
                if (isf32) {
                    acc0 = __builtin_amdgcn_mfma_f32_16x16x32_bf16(ah, wbl0[ks * 64 + lane], acc0, 0, 0, 0);
                    acc1 = __builtin_amdgcn_mfma_f32_16x16x32_bf16(ah, wbl1[ks * 64 + lane], acc1, 0, 0, 0);
                }
            }

            // wait rt(t-1) from this group's 16 P2 rows; finish gates (ksi 0..1)
            wait_flags16(rtf, ms * 16, (unsigned)t);
            #pragma unroll
            for (int ksi = 0; ksi < 2; ksi++) {
                int ks = 4 + ksi;
                short8 ah, al8;
                unpack_frag(AfPc64 + ((size_t)(ms * 18 + ksi) * 64 + lane) * 4, ah, al8);
                short8 bh0 = wb0[ks * 64 + lane];
                short8 bh1 = wb1[ks * 64 + lane];
                acc0 = __builtin_amdgcn_mfma_f32_16x16x32_bf16(ah, bh0, acc0, 0, 0, 0);
                acc0 = __builtin_amdgcn_mfma_f32_16x16x32_bf16(al8, bh0, acc0, 0, 0, 0);
                acc1 = __builtin_amdgcn_mfma_f32_16x16x32_bf16(ah, bh1, acc1, 0, 0, 0);
                acc1 = __builtin_amdgcn_mfma_f32_16x16x32_bf16(al8, bh1, acc1, 0, 0, 0);
                if (isf32) {
                    acc0 = __builtin_amdgcn_mfma_f32_16x16x32_bf16(ah, wbl0[ks * 64 + lane], acc0, 0, 0, 0);
                    acc1 = __builtin_amdgcn_mfma_f32_16x16x32_bf16(ah, wbl1[ks * 64 + lane], acc1, 0, 0, 0);
                }
            }
            {
                int n = lane & 15, m0 = (lane >> 4) * 4;
                #pragma unroll
                for (int r = 0; r < 4; r++) scr[wv][m0 + r][n] = acc0[r];
                #pragma unroll
                for (int r = 0; r < 4; r++) scr[wv + 4][m0 + r][n] = acc1[r];
            }
            __syncthreads();
            // cell epilogue: thread = (row r, units p and p+16); h -> hlh/hll bf16
            {
                int r = tid >> 4, p = tid & 15;
                float4 g = *(const float4*)&scr[p >> 2][r][(p & 3) * 4];
                float4 bb = *(const float4*)&bcS[p * 4];
                float c2 = sigmoidf_(g.y + bb.y) * cc0 + sigmoidf_(g.x + bb.x) * tanhf(g.z + bb.z);
                float h2 = sigmoidf_(g.w + bb.w) * tanhf(c2);
                cc0 = c2;
                unsigned short hi0 = f2bfbits(h2);
                hlh[r * 40 + p] = hi0;
                hll[r * 40 + p] = f2bfbits(h2 - bfbits2f(hi0));
                int u1 = p + 16;
                float4 g1 = *(const float4*)&scr[u1 >> 2][r][(u1 & 3) * 4];
                float4 bb1 = *(const float4*)&bcS[u1 * 4];
                float c21 = sigmoidf_(g1.y + bb1.y) * cc1 + sigmoidf_(g1.x + bb1.x) * tanhf(g1.z + bb1.z);
                float h21 = sigmoidf_(g1.w + bb1.w) * tanhf(c21);
                cc1 = c21;
                unsigned short hi1 = f2bfbits(h21);
                hlh[r * 40 + u1] = hi1;
                hll[r * 40 + u1] = f2bfbits(h21 - bfbits2f(hi1));
            }
            __syncthreads();
            // h publish: 256 threads, 2 cols each (already-converted bf16 hi/lo)
            {
                int rr = tid >> 4, pp = tid & 15;
                unsigned short hb0 = hlh[rr * 40 + 2 * pp];
                unsigned short lb0 = hll[rr * 40 + 2 * pp];
                unsigned short hb1 = hlh[rr * 40 + 2 * pp + 1];
                unsigned short lb1 = hll[rr * 40 + 2 * pp + 1];
                unsigned u0 = (unsigned)hb0 | ((unsigned)lb0 << 16);
                unsigned u1 = (unsigned)hb1 | ((unsigned)lb1 << 16);
                int u_g = gb * 32 + 2 * pp;
                int ksi2 = 2 + (u_g >> 5), q = (u_g & 31) >> 3, e = u_g & 7;
                size_t fi = (((size_t)ms * 18 + ksi2) * 64 + q * 16 + rr) * 8 + e;
                astore64(AfPn64 + fi / 2, (unsigned long long)u0 | ((unsigned long long)u1 << 32));
            }
            // drain h stores, publish hfl (unblocks the group's next iteration)
            asm volatile("s_waitcnt vmcnt(0)" ::: "memory");
            __syncthreads();
            if (tid == 0)
                __hip_atomic_store(&hfl[(ms * 16 + gb) * 16], (unsigned)(t + 1),
                                   __ATOMIC_RELAXED, __HIP_MEMORY_SCOPE_AGENT);

            // readout partials via MFMA: pt[16][224] = h(bf16 hi/lo) @ WrB
            {
                int m = lane & 15, q = lane >> 4;
                short8 ahh = *(const short8*)&hlh[m * 40 + q * 8];
                short8 ahl = *(const short8*)&hll[m * 40 + q * 8];
                int n = lane & 15, m0 = (lane >> 4) * 4;
                for (int jt = wv; jt < 14; jt += 4) {
                    const short8* bB  = (const short8*)&wrslB[((size_t)jt * 64 + lane) * 8];
                    const short8* bBl = (const short8*)&wrslBL[((size_t)jt * 64 + lane) * 8];
                    floatx4 accR = {0.f, 0.f, 0.f, 0.f};
                    short8 bh = *bB;
                    accR = __builtin_amdgcn_mfma_f32_16x16x32_bf16(ahh, bh, accR, 0, 0, 0);
                    accR = __builtin_amdgcn_mfma_f32_16x16x32_bf16(ahl, bh, accR, 0, 0, 0);
                    if (isf32) {
                        short8 bl = *bBl;
                        accR = __builtin_amdgcn_mfma_f32_16x16x32_bf16(ahh, bl, accR, 0, 0, 0);
                        accR = __builtin_amdgcn_mfma_f32_16x16x32_bf16(ahl, bl, accR, 0, 0, 0);
                    }
                    #pragma unroll
                    for (int ri = 0; ri < 4; ri++)
                        pt[(m0 + ri) * PTJ + jt * 16 + n] = accR[ri];
                }
            }
            __syncthreads();
            // part publish: wave wv rows 4wv..4wv+3; t<129 trim (ot unused)
            {
                #pragma unroll
                for (int it = 0; it < 4; it++) {
                    int rloc = wv * 4 + it;
                    int prow_ = ms * 16 + rloc;
                    const float* pr = pt + rloc * PTJ;
                    unsigned long long* pb64 =
                        (unsigned long long*)(part + (((size_t)prow_ * NGATE) + gb) * PJ);
                    if (use_x) {
                        if (lane < 32)
                            astore64(pb64 + lane, packf2(pr[2 * lane], pr[2 * lane + 1]));
                        else if (lane < 42) {
                            int l2 = lane - 32;   // u64 slots 96..105 = j 192..211
                            astore64(pb64 + 96 + l2,
                                     packf2(pr[192 + 2 * l2], pr[193 + 2 * l2]));
                        }
                    } else {
                        astore64(pb64 + lane, packf2(pr[2 * lane], pr[2 * lane + 1]));
                        if (lane < 40)
                            astore64(pb64 + 64 + lane,
                                     packf2(pr[128 + 2 * lane], pr[129 + 2 * lane]));
                    }
                }
            }
            // drain part stores, publish pfl (consumed only by P2 blocks)
            asm volatile("s_waitcnt vmcnt(0)" ::: "memory");
            __syncthreads();
            if (tid == 0)
                __hip_atomic_store(&pfl[(ms * 16 + gb) * 16], (unsigned)(t + 1),
                                   __ATOMIC_RELAXED, __HIP_MEMORY_SCOPE_AGENT);
        }
    } else {
        // ============================ P2 BLOCK ============================
        unsigned short* Vrow = Vg + (size_t)p2row * MAXT * SDIM;
        for (int t = 0; t < MAXT; t++) {
            unsigned long long* AfPn64 =
                (unsigned long long*)(AfP + (size_t)((t + 1) & 1) * AFRAG_U);

            // wait part(t) from all 16 gate blocks of this group
            wait_flags16(pfl, ms * 16, (unsigned)(t + 1));

            if (tid < 208) {
                const unsigned* pb2 = (const unsigned*)part
                                    + (size_t)p2row * NGATE * PJ + tid;
                float s4 = brS[tid];
                #pragma unroll
                for (int g = 0; g < NGATE; g++)
                    s4 += __builtin_bit_cast(float, aload(pb2 + (size_t)g * PJ));
                outs[tid] = s4;
            }
            __syncthreads();
            if (wv == 0) {
                float uval = sigmoidf_(outs[192]);
                float dval = sigmoidf_(outs[193]);
                Vrow[t * SDIM + lane] = f2bfbits(outs[lane]);
                int ebase = lane * 5;
                float sv[5], suf[5];
                #pragma unroll
                for (int j = 0; j < 5; j++) {
                    int e = ebase + j;
                    sv[j] = (e < MAXT) ? sL[e] : 0.f;
                }
                suf[4] = sv[4];
                #pragma unroll
                for (int j = 3; j >= 0; j--) suf[j] = sv[j] + suf[j + 1];
                float ltot = suf[0];
                float accs = ltot;
                #pragma unroll
                for (int off = 1; off < 64; off <<= 1) {
                    float y = __shfl_down(accs, off, 64);
                    if (lane + off < 64) accs += y;
                }
                float after_lane = accs - ltot;
                int emin = 0x7fffffff;
                #pragma unroll
                for (int j = 0; j < 5; j++) {
                    int e = ebase + j;
                    if (e <= t) {
                        float prod = after_lane + (suf[j] - sv[j]);
                        float sp = (e == t) ? dval
                                            : fmaxf(0.f, sv[j] - fmaxf(0.f, uval - prod));
                        float inner = fmaxf(0.f, 1.f - prod - sp);
                        sL[e] = sp;
                        aL[e] = fminf(sp, inner);
                        // A[e] nonzero only where prod < 1 (monotone suffix)
                        if (prod < 1.f && e < emin) emin = e;
                    }
                }
                #pragma unroll
                for (int off = 32; off; off >>= 1) {
                    int o = __shfl_xor(emin, off, 64);
                    emin = o < emin ? o : emin;
                }
                if (lane == 0) e0S = emin;
            }
            __syncthreads();
            {
                const int e0 = e0S;
                float racc = 0.f;
                if (e0 <= t) {
                    int i2s = e0 + ((wv - e0) & 3);
                    for (int i2 = i2s; i2 <= t; i2 += 4)
                        racc += aL[i2] * bfbits2f(Vrow[i2 * SDIM + lane]);
                }
                red[wv][lane] = racc;
            }
            __syncthreads();
            if (wv == 0) {
                float rtv = red[0][lane] + red[1][lane] + red[2][lane] + red[3][lane];
                float rtn = __shfl_down(rtv, 1, 64);
                if ((lane & 1) == 0) {
                    unsigned short hb0 = f2bfbits(rtv);
                    unsigned short lb0 = f2bfbits(rtv - bfbits2f(hb0));
                    unsigned short hb1 = f2bfbits(rtn);
                    unsigned short lb1 = f2bfbits(rtn - bfbits2f(hb1));
                    unsigned u0 = (unsigned)hb0 | ((unsigned)lb0 << 16);
                    unsigned u1 = (unsigned)hb1 | ((unsigned)lb1 << 16);
                    int d0 = lane;
                    int ksi = d0 >> 5, q = (d0 & 31) >> 3, e = d0 & 7;
                    size_t fi = (((size_t)ms * 18 + ksi) * 64 + q * 16 + pb) * 8 + e;
                    astore64(AfPn64 + fi / 2,
                             (unsigned long long)u0 | ((unsigned long long)u1 << 32));
                }
                asm volatile("s_waitcnt vmcnt(0)" ::: "memory");
                if (lane == 0)
                    __hip_atomic_store(&rtf[(ms * 16 + pb) * 16], (unsigned)(t + 1),
                                       __ATOMIC_RELAXED, __HIP_MEMORY_SCOPE_AGENT);
            } else if (wv == 1 && t >= 129) {
                float a = outs[64 + lane];
                float bvv = outs[128 + lane];
                float m = fmaxf(a, bvv);
                #pragma unroll
                for (int off = 32; off; off >>= 1) m = fmaxf(m, __shfl_xor(m, off, 64));
                float e = expf(a - m) + expf(bvv - m);
                #pragma unroll
                for (int off = 32; off; off >>= 1) e += __shfl_xor(e, off, 64);
                float ls = logf(e) + m;
                size_t base = ((size_t)(t - 129) * BATCH + p2row) * IDIM;
                if (isf32) {
                    ((float*)dout)[base + lane] = a - ls;
                    ((float*)dout)[base + lane + 64] = bvv - ls;
                } else {
                    ((bf16*)dout)[base + lane] = __float2bfloat16(a - ls);
                    ((bf16*)dout)[base + lane + 64] = __float2bfloat16(bvv - ls);
                }
            }
        }
    }
}

extern "C" void kernel_launch(void* const* d_in, const int* in_sizes, int n_in,
                              void* d_out, int out_size, void* d_ws, size_t ws_size,
                              hipStream_t stream) {
    const void* x   = d_in[0];
    const void* Wih = d_in[1];
    const void* bih = d_in[2];
    const void* Whh = d_in[3];
    const void* bhh = d_in[4];
    const void* Wr  = d_in[5];
    const void* br  = d_in[6];

    char* base = (char*)d_ws;
    size_t off = 0;
    int* flag = (int*)base;                                   off += 64;
    unsigned* hfl = (unsigned*)(base + off);                  off += 128 * 64 + 64;
    unsigned* pfl = (unsigned*)(base + off);                  off += 128 * 64 + 64;
    unsigned* rtf = (unsigned*)(base + off);                  off += 128 * 64 + 64;
    unsigned short* WfH  = (unsigned short*)(base + off);     off += (size_t)G4 * KTOT * 2;
    unsigned short* WfL  = (unsigned short*)(base + off);     off += (size_t)G4 * KTOT * 2;
    unsigned short* WrBh = (unsigned short*)(base + off);     off += (size_t)224 * HDIM * 2;
    unsigned short* WrBl = (unsigned short*)(base + off);     off += (size_t)224 * HDIM * 2;
    float* bc   = (float*)(base + off);                       off += G4 * 4;
    float* brf  = (float*)(base + off);                       off += 1024;
    unsigned* AfP = (unsigned*)(base + off);                  size_t af_off = off;
                                                              off += (size_t)2 * AFRAG_U * 4;
    float* part = (float*)(base + off);                       off += (size_t)BATCH * NGATE * PJ * 4;
    unsigned short* Vg = (unsigned short*)(base + off);       off += (size_t)BATCH * MAXT * SDIM * 2;
    // total ~14 MB

    hipMemsetAsync(base + 64, 0, 3 * (128 * 64 + 64), stream);         // hfl/pfl/rtf
    hipMemsetAsync(base + af_off, 0, (size_t)2 * AFRAG_U * 4, stream); // A-frag buffers
    hipMemsetAsync(part, 0, (size_t)BATCH * NGATE * PJ * 4, stream);   // stale-read hygiene

    detect_kernel<<<1, 64, 0, stream>>>((const unsigned short*)Wih, flag);
    prep_kernel<<<G4, 256, 0, stream>>>(Wih, bih, Whh, bhh, WfH, WfL, bc, flag);
    wr_prep_kernel<<<224, 256, 0, stream>>>(Wr, br, WrBh, WrBl, brf, flag);

    persist_kernel<<<NBLK, 256, 0, stream>>>(x, WfH, WfL, bc, WrBh, WrBl, brf,
                                             AfP, part, Vg, d_out, flag,
                                             hfl, pfl, rtf);

    (void)in_sizes; (void)n_in; (void)out_size; (void)ws_size;
}

// Round 8
// 3075.033 us; speedup vs baseline: 1.2147x; 1.2147x over previous
//
#include <hip/hip_runtime.h>
#include <hip/hip_bf16.h>
#include <math.h>

#define IDIM 128
#define HDIM 512
#define SDIM 64
#define BATCH 128
#define MAXT 259
#define G4 2048
#define KTOT 704    // 128 (x) + 64 (rt) + 512 (h)
#define ROUT 194    // 64 + 128 + 2
#define AFRAG_U 73728   // 8 mt * 18 ks * 64 lanes * 8 e (uints, hi|lo packed) per buffer
#define NBLK 256
#define NGATE 16    // gate blocks per group
#define PTJ 224     // pt row stride (14 j-tiles x 16)
#define PCJ 80      // partC per-(row,gb) f32 stride: 64 vt + u,d + pad
#define POJ 128     // partO per-(row,gb) f32 stride: ot cols

typedef __hip_bfloat16 bf16;
typedef __attribute__((ext_vector_type(8))) short short8;
typedef __attribute__((ext_vector_type(4))) float floatx4;

__device__ __forceinline__ float sigmoidf_(float v) { return 1.f / (1.f + expf(-v)); }
__device__ __forceinline__ float b2f(bf16 v) { return __bfloat162float(v); }
__device__ __forceinline__ float load_in(const void* p, size_t i, int isf32) {
    return isf32 ? ((const float*)p)[i] : b2f(((const bf16*)p)[i]);
}
__device__ __forceinline__ unsigned short f2bfbits(float v) {
    unsigned u = __builtin_bit_cast(unsigned, v);
    unsigned r = (u + 0x7FFFu + ((u >> 16) & 1u)) >> 16;
    return (unsigned short)r;
}
__device__ __forceinline__ float bfbits2f(unsigned short b) {
    return __builtin_bit_cast(float, (unsigned)b << 16);
}
__device__ __forceinline__ unsigned aload(const unsigned* p) {
    return __hip_atomic_load(p, __ATOMIC_RELAXED, __HIP_MEMORY_SCOPE_AGENT);
}
__device__ __forceinline__ unsigned long long aload64(const unsigned long long* p) {
    return __hip_atomic_load(p, __ATOMIC_RELAXED, __HIP_MEMORY_SCOPE_AGENT);
}
__device__ __forceinline__ void astore64(unsigned long long* p, unsigned long long v) {
    __hip_atomic_store(p, v, __ATOMIC_RELAXED, __HIP_MEMORY_SCOPE_AGENT);
}
__device__ __forceinline__ unsigned long long packf2(float a, float b) {
    return (unsigned long long)__builtin_bit_cast(unsigned, a)
         | ((unsigned long long)__builtin_bit_cast(unsigned, b) << 32);
}
__device__ __forceinline__ void unpack_frag(const unsigned long long* ap,
                                            short8& ah, short8& al) {
    #pragma unroll
    for (int j = 0; j < 4; j++) {
        unsigned long long q = aload64(ap + j);
        unsigned u0 = (unsigned)q, u1 = (unsigned)(q >> 32);
        ah[2 * j]     = (short)(u0 & 0xffffu);
        al[2 * j]     = (short)(u0 >> 16);
        ah[2 * j + 1] = (short)(u1 & 0xffffu);
        al[2 * j + 1] = (short)(u1 >> 16);
    }
}

// Poll 16 consecutive epoch flags (stride-16 uints) until all >= tgt.
// Producers store flags AFTER a per-wave vmcnt drain of their data stores
// (+ __syncthreads across the block) -> flag >= tgt implies data visible.
__device__ __forceinline__ void wait_flags16(const unsigned* f, int base16,
                                             unsigned tgt) {
    if (threadIdx.x < 16) {
        while (aload(&f[(base16 + (int)threadIdx.x) * 16]) < tgt)
            __builtin_amdgcn_s_sleep(1);
    }
    __atomic_signal_fence(__ATOMIC_SEQ_CST);
    __syncthreads();
}

// dtype detect (defensive): f32 data has random low halves -> bf16-exp >= 0x8F
__global__ void detect_kernel(const unsigned short* __restrict__ w, int* __restrict__ flag) {
    if (threadIdx.x == 0) {
        int isf32 = 0;
        for (int i = 0; i < 256; i++) {
            int e = (w[i] >> 7) & 0xFF;
            if (e >= 0x8F) isf32 = 1;
        }
        *flag = isf32;
    }
}

// Gate-interleaved combined weights in B-fragment layout (hi/lo bf16 split).
__global__ void prep_kernel(const void* __restrict__ Wih, const void* __restrict__ bih,
                            const void* __restrict__ Whh, const void* __restrict__ bhh,
                            unsigned short* __restrict__ WfH, unsigned short* __restrict__ WfL,
                            float* __restrict__ bc, const int* __restrict__ flag) {
    int isf32 = *flag;
    int jp = blockIdx.x;
    int u = jp >> 2, gate = jp & 3;
    int src = gate * HDIM + u;
    int jt = jp >> 4, jn = jp & 15;
    for (int k = threadIdx.x; k < KTOT; k += blockDim.x) {
        float v = (k < 192) ? load_in(Wih, (size_t)src * 192 + k, isf32)
                            : load_in(Whh, (size_t)src * HDIM + (k - 192), isf32);
        unsigned short hi = f2bfbits(v);
        unsigned short lo = f2bfbits(v - bfbits2f(hi));
        int ks = k >> 5, q = (k & 31) >> 3, e = k & 7;
        size_t d = (((size_t)jt * 22 + ks) * 64 + (q * 16 + jn)) * 8 + e;
        WfH[d] = hi;
        WfL[d] = lo;
    }
    if (threadIdx.x == 0)
        bc[jp] = load_in(bih, src, isf32) + load_in(bhh, src, isf32);
}

// Wr -> row-major bf16 hi/lo (224 rows, rows >= 194 zero) + brf f32 (padded).
__global__ void wr_prep_kernel(const void* __restrict__ Wr, const void* __restrict__ br,
                               unsigned short* __restrict__ WrBh, unsigned short* __restrict__ WrBl,
                               float* __restrict__ brf, const int* __restrict__ flag) {
    int isf32 = *flag;
    int j = blockIdx.x;
    for (int k = threadIdx.x; k < HDIM; k += blockDim.x) {
        float v = (j < ROUT) ? load_in(Wr, (size_t)j * HDIM + k, isf32) : 0.f;
        unsigned short hi = f2bfbits(v);
        WrBh[(size_t)j * HDIM + k] = hi;
        WrBl[(size_t)j * HDIM + k] = f2bfbits(v - bfbits2f(hi));
    }
    if (threadIdx.x == 0) brf[j] = (j < ROUT) ? load_in(br, j, isf32) : 0.f;
}

// ---- persistent kernel (R19 = verified R15 + x-hoist + crit/ot readout split) ----
// Differences from R15 (3012us, passing):
//   (a) x-MFMA hoisted before the hfl wait (independent of h(t-1));
//   (b) readout split: crit tiles {0,1,2,3,12} (vt + u,d) -> partC -> pfl
//       immediately; ot tiles {4..11} computed/published ONLY for t>=129 into
//       parity-double-buffered partO + oflg flag (off the rt-critical loop).
//       WAR proof for partO parity p: gates overwrite at t+2 only after
//       rtf>=t+2, posted in P2 iter t+1 which serially follows softmax(t).
//   (c) tile 13 (zero rows) never computed.
// Frag staging, gate MFMA, epilogue, h publish, P2 scan/einsum/rt: R15 verbatim.
__global__ __launch_bounds__(256) void persist_kernel(
        const void* __restrict__ x,
        const unsigned short* __restrict__ WfH, const unsigned short* __restrict__ WfL,
        const float* __restrict__ bc,
        const unsigned short* __restrict__ WrBh, const unsigned short* __restrict__ WrBl,
        const float* __restrict__ brf,
        unsigned* __restrict__ AfP,          // 2 x AFRAG_U uints (hi | lo<<16)
        float* __restrict__ partC,           // [128 rows][16 gb][PCJ] f32 (vt,u,d)
        float* __restrict__ partO,           // [2][128 rows][16 gb][POJ] f32 (ot)
        unsigned short* __restrict__ Vg,     // [128][259][64] bf16, row-private
        void* __restrict__ dout, const int* __restrict__ flag,
        unsigned* __restrict__ hfl, unsigned* __restrict__ pfl,
        unsigned* __restrict__ rtf, unsigned* __restrict__ oflg) {
    __shared__ __align__(16) short Ahs[18 * 64 * 8];          // staged A hi; pt overlay
    __shared__ __align__(16) short Als[18 * 64 * 8];          // staged A lo
    __shared__ __align__(16) unsigned short wrslB[14 * 64 * 8];   // Wr hi, B-frag layout
    __shared__ __align__(16) unsigned short wrslBL[14 * 64 * 8];  // Wr lo, B-frag layout
    __shared__ __align__(16) float scr[8][16][20];
    __shared__ __align__(16) unsigned short hlh[16 * 40];     // h hi bf16 (pad 40)
    __shared__ __align__(16) unsigned short hll[16 * 40];     // h lo bf16
    __shared__ __align__(16) float outsC[80];                 // vt(64) + u,d
    __shared__ __align__(16) float sL[324];
    __shared__ __align__(16) float aL[324];
    __shared__ __align__(16) float red[4][64];
    __shared__ __align__(16) float redo[128][2];
    __shared__ __align__(16) float oL[128];
    __shared__ __align__(16) float brS[208];
    __shared__ __align__(16) float bcS[128];
    __shared__ int e0S;

    const int tid = threadIdx.x, lane = tid & 63, wv = tid >> 6;
    const int blk = blockIdx.x, ms = blk >> 5, ns = blk & 31;
    const int isf32 = *flag;
    float* const pt = (float*)Ahs;       // 16 x PTJ f32 overlay (14.3KB <= 18.4KB)

    const int is_gate = (ns < 16);
    const int gb = ns;                   // gate block index (when is_gate)
    const int pb = ns - 16;              // P2 index (when !is_gate)
    const int p2row = ms * 16 + pb;      // P2's batch row

    if (is_gate) {
        // Wr slice in B-frag layout: tile jt (14), lane l, elem e ->
        // row j = jt*16 + (l&15), col k = gb*32 + (l>>4)*8 + e.
        for (int i = tid; i < 14 * 64 * 8; i += 256) {
            int jt = i >> 9, l = (i >> 3) & 63, e = i & 7;
            size_t src = (size_t)(jt * 16 + (l & 15)) * HDIM + gb * 32 + (l >> 4) * 8 + e;
            wrslB[i]  = WrBh[src];
            wrslBL[i] = WrBl[src];
        }
        if (tid < 128) bcS[tid] = bc[gb * 128 + tid];
    } else {
        for (int i = tid; i < 208; i += 256) brS[i] = brf[i];
        for (int i = tid; i < 324; i += 256) { sL[i] = 0.f; aL[i] = 0.f; }
    }
    __syncthreads();

    if (is_gate) {
        // =========================== GATE BLOCK ===========================
        const short8* WH = (const short8*)WfH;
        const short8* WL = (const short8*)WfL;
        const int jt0 = gb * 8 + wv, jt1 = gb * 8 + 4 + wv;
        const short8* wb0  = WH + (size_t)jt0 * 22 * 64;
        const short8* wb1  = WH + (size_t)jt1 * 22 * 64;
        const short8* wbl0 = WL + (size_t)jt0 * 22 * 64;
        const short8* wbl1 = WL + (size_t)jt1 * 22 * 64;
        float cc0 = 0.f, cc1 = 0.f;

        for (int t = 0; t < MAXT; t++) {
            const int cur = t & 1, nxt = cur ^ 1;
            const unsigned long long* AfPc64 =
                (const unsigned long long*)(AfP + (size_t)cur * AFRAG_U);
            unsigned long long* AfPn64 =
                (unsigned long long*)(AfP + (size_t)nxt * AFRAG_U);
            const int use_x = (t < 129);

            // P1-x: x MFMAs BEFORE the h wait (independent of h(t-1))
            floatx4 acc0 = {0.f, 0.f, 0.f, 0.f};
            floatx4 acc1 = {0.f, 0.f, 0.f, 0.f};
            if (use_x) {
                int m = lane & 15, q = lane >> 4;
                size_t xrow = ((size_t)t * BATCH + ms * 16 + m) * IDIM + q * 8;
                #pragma unroll
                for (int ks = 0; ks < 4; ks++) {
                    short8 a;
                    if (isf32) {
                        const float* xf = (const float*)x + xrow + ks * 32;
                        #pragma unroll
                        for (int i = 0; i < 8; i++) a[i] = (short)f2bfbits(xf[i]);
                    } else {
                        a = *(const short8*)((const unsigned short*)x + xrow + ks * 32);
                    }
                    acc0 = __builtin_amdgcn_mfma_f32_16x16x32_bf16(a, wb0[ks * 64 + lane], acc0, 0, 0, 0);
                    acc1 = __builtin_amdgcn_mfma_f32_16x16x32_bf16(a, wb1[ks * 64 + lane], acc1, 0, 0, 0);
                    if (isf32) {
                        acc0 = __builtin_amdgcn_mfma_f32_16x16x32_bf16(a, wbl0[ks * 64 + lane], acc0, 0, 0, 0);
                        acc1 = __builtin_amdgcn_mfma_f32_16x16x32_bf16(a, wbl1[ks * 64 + lane], acc1, 0, 0, 0);
                    }
                }
            }

            // wait h(t-1) frags from all 16 P2 rows, then stage to LDS (R15)
            wait_flags16(hfl, ms * 16, (unsigned)t);
            #pragma unroll
            for (int i0 = 0; i0 < 4; i0++) {
                int i = i0 * 256 + tid;
                int ksi = 2 + (i >> 6), l = i & 63;
                const unsigned long long* ap =
                    AfPc64 + ((size_t)(ms * 18 + ksi) * 64 + l) * 4;
                short8 ah, al8;
                unpack_frag(ap, ah, al8);
                *(short8*)&Ahs[(ksi * 64 + l) * 8] = ah;
                *(short8*)&Als[(ksi * 64 + l) * 8] = al8;
            }
            __syncthreads();

            // h MFMAs (ksi 2..17) from LDS (R15 verbatim)
            #pragma unroll 4
            for (int ksi = 2; ksi < 18; ksi++) {
                int ks = 4 + ksi;
                short8 ah  = *(const short8*)&Ahs[(ksi * 64 + lane) * 8];
                short8 al8 = *(const short8*)&Als[(ksi * 64 + lane) * 8];
                short8 bh0 = wb0[ks * 64 + lane];
                short8 bh1 = wb1[ks * 64 + lane];
                acc0 = __builtin_amdgcn_mfma_f32_16x16x32_bf16(ah, bh0, acc0, 0, 0, 0);
                acc0 = __builtin_amdgcn_mfma_f32_16x16x32_bf16(al8, bh0, acc0, 0, 0, 0);
                acc1 = __builtin_amdgcn_mfma_f32_16x16x32_bf16(ah, bh1, acc1, 0, 0, 0);
                acc1 = __builtin_amdgcn_mfma_f32_16x16x32_bf16(al8, bh1, acc1, 0, 0, 0);
                if (isf32) {
                    acc0 = __builtin_amdgcn_mfma_f32_16x16x32_bf16(ah, wbl0[ks * 64 + lane], acc0, 0, 0, 0);
                    acc1 = __builtin_amdgcn_mfma_f32_16x16x32_bf16(ah, wbl1[ks * 64 + lane], acc1, 0, 0, 0);
                }
            }

            // wait rt(t-1); stage rt frags (ksi 0..1); finish gates (R15)
            wait_flags16(rtf, ms * 16, (unsigned)t);
            if (tid < 128) {
                int ksi = tid >> 6, l = tid & 63;
                const unsigned long long* ap =
                    AfPc64 + ((size_t)(ms * 18 + ksi) * 64 + l) * 4;
                short8 ah, al8;
                unpack_frag(ap, ah, al8);
                *(short8*)&Ahs[(ksi * 64 + l) * 8] = ah;
                *(short8*)&Als[(ksi * 64 + l) * 8] = al8;
            }
            __syncthreads();
            #pragma unroll
            for (int ksi = 0; ksi < 2; ksi++) {
                int ks = 4 + ksi;
                short8 ah  = *(const short8*)&Ahs[(ksi * 64 + lane) * 8];
                short8 al8 = *(const short8*)&Als[(ksi * 64 + lane) * 8];
                short8 bh0 = wb0[ks * 64 + lane];
                short8 bh1 = wb1[ks * 64 + lane];
                acc0 = __builtin_amdgcn_mfma_f32_16x16x32_bf16(ah, bh0, acc0, 0, 0, 0);
                acc0 = __builtin_amdgcn_mfma_f32_16x16x32_bf16(al8, bh0, acc0, 0, 0, 0);
                acc1 = __builtin_amdgcn_mfma_f32_16x16x32_bf16(ah, bh1, acc1, 0, 0, 0);
                acc1 = __builtin_amdgcn_mfma_f32_16x16x32_bf16(al8, bh1, acc1, 0, 0, 0);
                if (isf32) {
                    acc0 = __builtin_amdgcn_mfma_f32_16x16x32_bf16(ah, wbl0[ks * 64 + lane], acc0, 0, 0, 0);
                    acc1 = __builtin_amdgcn_mfma_f32_16x16x32_bf16(ah, wbl1[ks * 64 + lane], acc1, 0, 0, 0);
                }
            }
            {
                int n = lane & 15, m0 = (lane >> 4) * 4;
                #pragma unroll
                for (int r = 0; r < 4; r++) scr[wv][m0 + r][n] = acc0[r];
                #pragma unroll
                for (int r = 0; r < 4; r++) scr[wv + 4][m0 + r][n] = acc1[r];
            }
            __syncthreads();
            // cell epilogue (R15 verbatim)
            {
                int r = tid >> 4, p = tid & 15;
                float4 g = *(const float4*)&scr[p >> 2][r][(p & 3) * 4];
                float4 bb = *(const float4*)&bcS[p * 4];
                float c2 = sigmoidf_(g.y + bb.y) * cc0 + sigmoidf_(g.x + bb.x) * tanhf(g.z + bb.z);
                float h2 = sigmoidf_(g.w + bb.w) * tanhf(c2);
                cc0 = c2;
                unsigned short hi0 = f2bfbits(h2);
                hlh[r * 40 + p] = hi0;
                hll[r * 40 + p] = f2bfbits(h2 - bfbits2f(hi0));
                int u1 = p + 16;
                float4 g1 = *(const float4*)&scr[u1 >> 2][r][(u1 & 3) * 4];
                float4 bb1 = *(const float4*)&bcS[u1 * 4];
                float c21 = sigmoidf_(g1.y + bb1.y) * cc1 + sigmoidf_(g1.x + bb1.x) * tanhf(g1.z + bb1.z);
                float h21 = sigmoidf_(g1.w + bb1.w) * tanhf(c21);
                cc1 = c21;
                unsigned short hi1 = f2bfbits(h21);
                hlh[r * 40 + u1] = hi1;
                hll[r * 40 + u1] = f2bfbits(h21 - bfbits2f(hi1));
            }
            __syncthreads();   // hlh/hll ready; Ahs (MFMA staging) now dead -> pt overlay OK
            // h publish (R15 verbatim) + hfl
            {
                int rr = tid >> 4, pp = tid & 15;
                unsigned short hb0 = hlh[rr * 40 + 2 * pp];
                unsigned short lb0 = hll[rr * 40 + 2 * pp];
                unsigned short hb1 = hlh[rr * 40 + 2 * pp + 1];
                unsigned short lb1 = hll[rr * 40 + 2 * pp + 1];
                unsigned u0 = (unsigned)hb0 | ((unsigned)lb0 << 16);
                unsigned u1 = (unsigned)hb1 | ((unsigned)lb1 << 16);
                int u_g = gb * 32 + 2 * pp;
                int ksi2 = 2 + (u_g >> 5), q = (u_g & 31) >> 3, e = u_g & 7;
                size_t fi = (((size_t)ms * 18 + ksi2) * 64 + q * 16 + rr) * 8 + e;
                astore64(AfPn64 + fi / 2, (unsigned long long)u0 | ((unsigned long long)u1 << 32));
            }
            asm volatile("s_waitcnt vmcnt(0)" ::: "memory");
            __syncthreads();
            if (tid == 0)
                __hip_atomic_store(&hfl[(ms * 16 + gb) * 16], (unsigned)(t + 1),
                                   __ATOMIC_RELAXED, __HIP_MEMORY_SCOPE_AGENT);

            // crit readout via MFMA: tiles {wv} + wave0 tile 12 (vt + u,d)
            {
                int m = lane & 15, q = lane >> 4;
                short8 ahh = *(const short8*)&hlh[m * 40 + q * 8];
                short8 ahl = *(const short8*)&hll[m * 40 + q * 8];
                int n = lane & 15, m0 = (lane >> 4) * 4;
                #pragma unroll
                for (int sel = 0; sel < 2; sel++) {
                    int jt = sel == 0 ? wv : 12;
                    if (sel == 1 && wv != 0) break;
                    const short8* bB  = (const short8*)&wrslB[((size_t)jt * 64 + lane) * 8];
                    const short8* bBl = (const short8*)&wrslBL[((size_t)jt * 64 + lane) * 8];
                    floatx4 accR = {0.f, 0.f, 0.f, 0.f};
                    short8 bh = *bB;
                    accR = __builtin_amdgcn_mfma_f32_16x16x32_bf16(ahh, bh, accR, 0, 0, 0);
                    accR = __builtin_amdgcn_mfma_f32_16x16x32_bf16(ahl, bh, accR, 0, 0, 0);
                    if (isf32) {
                        short8 bl = *bBl;
                        accR = __builtin_amdgcn_mfma_f32_16x16x32_bf16(ahh, bl, accR, 0, 0, 0);
                        accR = __builtin_amdgcn_mfma_f32_16x16x32_bf16(ahl, bl, accR, 0, 0, 0);
                    }
                    #pragma unroll
                    for (int ri = 0; ri < 4; ri++)
                        pt[(m0 + ri) * PTJ + jt * 16 + n] = accR[ri];
                }
            }
            __syncthreads();
            // crit publish: wave wv rows 4wv..4wv+3; 33 u64 per row -> partC
            {
                #pragma unroll
                for (int it = 0; it < 4; it++) {
                    int rloc = wv * 4 + it;
                    int prow_ = ms * 16 + rloc;
                    const float* pr = pt + rloc * PTJ;
                    unsigned long long* pb64 =
                        (unsigned long long*)(partC + (((size_t)prow_ * NGATE) + gb) * PCJ);
                    if (lane < 32)
                        astore64(pb64 + lane, packf2(pr[2 * lane], pr[2 * lane + 1]));
                    else if (lane == 32)
                        astore64(pb64 + 32, packf2(pr[192], pr[193]));
                }
            }
            asm volatile("s_waitcnt vmcnt(0)" ::: "memory");
            __syncthreads();
            if (tid == 0)
                __hip_atomic_store(&pfl[(ms * 16 + gb) * 16], (unsigned)(t + 1),
                                   __ATOMIC_RELAXED, __HIP_MEMORY_SCOPE_AGENT);

            // ot readout + publish, ONLY t>=129 (parity buffer; off crit loop)
            if (!use_x) {
                {
                    int m = lane & 15, q = lane >> 4;
                    short8 ahh = *(const short8*)&hlh[m * 40 + q * 8];
                    short8 ahl = *(const short8*)&hll[m * 40 + q * 8];
                    int n = lane & 15, m0 = (lane >> 4) * 4;
                    #pragma unroll
                    for (int s2 = 0; s2 < 2; s2++) {
                        int jt = 4 + wv + s2 * 4;
                        const short8* bB  = (const short8*)&wrslB[((size_t)jt * 64 + lane) * 8];
                        const short8* bBl = (const short8*)&wrslBL[((size_t)jt * 64 + lane) * 8];
                        floatx4 accR = {0.f, 0.f, 0.f, 0.f};
                        short8 bh = *bB;
                        accR = __builtin_amdgcn_mfma_f32_16x16x32_bf16(ahh, bh, accR, 0, 0, 0);
                        accR = __builtin_amdgcn_mfma_f32_16x16x32_bf16(ahl, bh, accR, 0, 0, 0);
                        if (isf32) {
                            short8 bl = *bBl;
                            accR = __builtin_amdgcn_mfma_f32_16x16x32_bf16(ahh, bl, accR, 0, 0, 0);
                            accR = __builtin_amdgcn_mfma_f32_16x16x32_bf16(ahl, bl, accR, 0, 0, 0);
                        }
                        #pragma unroll
                        for (int ri = 0; ri < 4; ri++)
                            pt[(m0 + ri) * PTJ + jt * 16 + n] = accR[ri];
                    }
                }
                __syncthreads();
                {
                    #pragma unroll
                    for (int it = 0; it < 4; it++) {
                        int rloc = wv * 4 + it;
                        int prow_ = ms * 16 + rloc;
                        const float* pr = pt + rloc * PTJ;
                        unsigned long long* pb64 = (unsigned long long*)
                            (partO + ((((size_t)cur * BATCH + prow_) * NGATE) + gb) * POJ);
                        astore64(pb64 + lane, packf2(pr[64 + 2 * lane], pr[65 + 2 * lane]));
                    }
                }
                asm volatile("s_waitcnt vmcnt(0)" ::: "memory");
                __syncthreads();
                if (tid == 0)
                    __hip_atomic_store(&oflg[(ms * 16 + gb) * 16], (unsigned)(t + 1),
                                       __ATOMIC_RELAXED, __HIP_MEMORY_SCOPE_AGENT);
            }
        }
    } else {
        // ============================ P2 BLOCK ============================
        unsigned short* Vrow = Vg + (size_t)p2row * MAXT * SDIM;
        for (int t = 0; t < MAXT; t++) {
            unsigned long long* AfPn64 =
                (unsigned long long*)(AfP + (size_t)((t + 1) & 1) * AFRAG_U);

            // wait crit partials(t) from all 16 gate blocks of this group
            wait_flags16(pfl, ms * 16, (unsigned)(t + 1));

            if (tid < 66) {
                const unsigned* pb2 = (const unsigned*)partC
                                    + (size_t)p2row * NGATE * PCJ + tid;
                float s4 = (tid < 64) ? brS[tid] : brS[128 + tid];  // 64->192, 65->193
                #pragma unroll
                for (int g = 0; g < NGATE; g++)
                    s4 += __builtin_bit_cast(float, aload(pb2 + (size_t)g * PCJ));
                outsC[tid] = s4;
            }
            __syncthreads();
            if (wv == 0) {
                float uval = sigmoidf_(outsC[64]);
                float dval = sigmoidf_(outsC[65]);
                Vrow[t * SDIM + lane] = f2bfbits(outsC[lane]);
                int ebase = lane * 5;
                float sv[5], suf[5];
                #pragma unroll
                for (int j = 0; j < 5; j++) {
                    int e = ebase + j;
                    sv[j] = (e < MAXT) ? sL[e] : 0.f;
                }
                suf[4] = sv[4];
                #pragma unroll
                for (int j = 3; j >= 0; j--) suf[j] = sv[j] + suf[j + 1];
                float ltot = suf[0];
                float accs = ltot;
                #pragma unroll
                for (int off = 1; off < 64; off <<= 1) {
                    float y = __shfl_down(accs, off, 64);
                    if (lane + off < 64) accs += y;
                }
                float after_lane = accs - ltot;
                int emin = 0x7fffffff;
                #pragma unroll
                for (int j = 0; j < 5; j++) {
                    int e = ebase + j;
                    if (e <= t) {
                        float prod = after_lane + (suf[j] - sv[j]);
                        float sp = (e == t) ? dval
                                            : fmaxf(0.f, sv[j] - fmaxf(0.f, uval - prod));
                        float inner = fmaxf(0.f, 1.f - prod - sp);
                        sL[e] = sp;
                        aL[e] = fminf(sp, inner);
                        // A[e] nonzero only where prod < 1 (monotone suffix)
                        if (prod < 1.f && e < emin) emin = e;
                    }
                }
                #pragma unroll
                for (int off = 32; off; off >>= 1) {
                    int o = __shfl_xor(emin, off, 64);
                    emin = o < emin ? o : emin;
                }
                if (lane == 0) e0S = emin;
            }
            __syncthreads();
            {
                const int e0 = e0S;
                float racc = 0.f;
                if (e0 <= t) {
                    int i2s = e0 + ((wv - e0) & 3);
                    for (int i2 = i2s; i2 <= t; i2 += 4)
                        racc += aL[i2] * bfbits2f(Vrow[i2 * SDIM + lane]);
                }
                red[wv][lane] = racc;
            }
            __syncthreads();
            if (wv == 0) {
                float rtv = red[0][lane] + red[1][lane] + red[2][lane] + red[3][lane];
                float rtn = __shfl_down(rtv, 1, 64);
                if ((lane & 1) == 0) {
                    unsigned short hb0 = f2bfbits(rtv);
                    unsigned short lb0 = f2bfbits(rtv - bfbits2f(hb0));
                    unsigned short hb1 = f2bfbits(rtn);
                    unsigned short lb1 = f2bfbits(rtn - bfbits2f(hb1));
                    unsigned u0 = (unsigned)hb0 | ((unsigned)lb0 << 16);
                    unsigned u1 = (unsigned)hb1 | ((unsigned)lb1 << 16);
                    int d0 = lane;
                    int ksi = d0 >> 5, q = (d0 & 31) >> 3, e = d0 & 7;
                    size_t fi = (((size_t)ms * 18 + ksi) * 64 + q * 16 + pb) * 8 + e;
                    astore64(AfPn64 + fi / 2,
                             (unsigned long long)u0 | ((unsigned long long)u1 << 32));
                }
                asm volatile("s_waitcnt vmcnt(0)" ::: "memory");
                if (lane == 0)
                    __hip_atomic_store(&rtf[(ms * 16 + pb) * 16], (unsigned)(t + 1),
                                       __ATOMIC_RELAXED, __HIP_MEMORY_SCOPE_AGENT);
            }
            // output path (t >= 129): wait ot partials, reduce, log-softmax.
            // Safe vs WAR by partO parity (see kernel comment).
            if (t >= 129) {
                wait_flags16(oflg, ms * 16, (unsigned)(t + 1));
                {
                    int col = tid >> 1, half = tid & 1;
                    const unsigned* pbo = (const unsigned*)partO
                        + (((size_t)(t & 1) * BATCH + p2row) * NGATE) * POJ + col;
                    float s = 0.f;
                    #pragma unroll
                    for (int g = 0; g < 8; g++)
                        s += __builtin_bit_cast(float,
                                aload(pbo + (size_t)(half * 8 + g) * POJ));
                    redo[col][half] = s;
                }
                __syncthreads();
                if (tid < 128) oL[tid] = redo[tid][0] + redo[tid][1] + brS[64 + tid];
                __syncthreads();
                if (wv == 0) {
                    float a = oL[lane];
                    float bvv = oL[64 + lane];
                    float m = fmaxf(a, bvv);
                    #pragma unroll
                    for (int off = 32; off; off >>= 1) m = fmaxf(m, __shfl_xor(m, off, 64));
                    float e = expf(a - m) + expf(bvv - m);
                    #pragma unroll
                    for (int off = 32; off; off >>= 1) e += __shfl_xor(e, off, 64);
                    float ls = logf(e) + m;
                    size_t base = ((size_t)(t - 129) * BATCH + p2row) * IDIM;
                    if (isf32) {
                        ((float*)dout)[base + lane] = a - ls;
                        ((float*)dout)[base + lane + 64] = bvv - ls;
                    } else {
                        ((bf16*)dout)[base + lane] = __float2bfloat16(a - ls);
                        ((bf16*)dout)[base + lane + 64] = __float2bfloat16(bvv - ls);
                    }
                }
            }
        }
    }
}

extern "C" void kernel_launch(void* const* d_in, const int* in_sizes, int n_in,
                              void* d_out, int out_size, void* d_ws, size_t ws_size,
                              hipStream_t stream) {
    const void* x   = d_in[0];
    const void* Wih = d_in[1];
    const void* bih = d_in[2];
    const void* Whh = d_in[3];
    const void* bhh = d_in[4];
    const void* Wr  = d_in[5];
    const void* br  = d_in[6];

    char* base = (char*)d_ws;
    size_t off = 0;
    int* flag = (int*)base;                                   off += 64;
    unsigned* hfl = (unsigned*)(base + off);                  off += 128 * 64 + 64;
    unsigned* pfl = (unsigned*)(base + off);                  off += 128 * 64 + 64;
    unsigned* rtf = (unsigned*)(base + off);                  off += 128 * 64 + 64;
    unsigned* oflg = (unsigned*)(base + off);                 off += 128 * 64 + 64;
    unsigned short* WfH  = (unsigned short*)(base + off);     off += (size_t)G4 * KTOT * 2;
    unsigned short* WfL  = (unsigned short*)(base + off);     off += (size_t)G4 * KTOT * 2;
    unsigned short* WrBh = (unsigned short*)(base + off);     off += (size_t)224 * HDIM * 2;
    unsigned short* WrBl = (unsigned short*)(base + off);     off += (size_t)224 * HDIM * 2;
    float* bc   = (float*)(base + off);                       off += G4 * 4;
    float* brf  = (float*)(base + off);                       off += 1024;
    unsigned* AfP = (unsigned*)(base + off);                  size_t af_off = off;
                                                              off += (size_t)2 * AFRAG_U * 4;
    float* partC = (float*)(base + off);                      off += (size_t)BATCH * NGATE * PCJ * 4;
    float* partO = (float*)(base + off);                      off += (size_t)2 * BATCH * NGATE * POJ * 4;
    unsigned short* Vg = (unsigned short*)(base + off);       off += (size_t)BATCH * MAXT * SDIM * 2;
    // total ~14 MB

    hipMemsetAsync(base + 64, 0, 4 * (128 * 64 + 64), stream);         // hfl/pfl/rtf/oflg
    hipMemsetAsync(base + af_off, 0, (size_t)2 * AFRAG_U * 4, stream); // A-frag buffers
    hipMemsetAsync(partC, 0, (size_t)BATCH * NGATE * PCJ * 4, stream); // stale-read hygiene

    detect_kernel<<<1, 64, 0, stream>>>((const unsigned short*)Wih, flag);
    prep_kernel<<<G4, 256, 0, stream>>>(Wih, bih, Whh, bhh, WfH, WfL, bc, flag);
    wr_prep_kernel<<<224, 256, 0, stream>>>(Wr, br, WrBh, WrBl, brf, flag);

    persist_kernel<<<NBLK, 256, 0, stream>>>(x, WfH, WfL, bc, WrBh, WrBl, brf,
                                             AfP, partC, partO, Vg, d_out, flag,
                                             hfl, pfl, rtf, oflg);

    (void)in_sizes; (void)n_in; (void)out_size; (void)ws_size;
}

// Round 9
// 2982.390 us; speedup vs baseline: 1.2524x; 1.0311x over previous
//
#include <hip/hip_runtime.h>
#include <hip/hip_bf16.h>
#include <math.h>

#define IDIM 128
#define HDIM 512
#define SDIM 64
#define BATCH 128
#define MAXT 259
#define G4 2048
#define KTOT 704    // 128 (x) + 64 (rt) + 512 (h)
#define ROUT 194    // 64 + 128 + 2
#define AFRAG_U 73728   // 8 mt * 18 ks * 64 lanes * 8 e (uints, hi|lo packed) per buffer
#define NBLK 256
#define NGATE 16    // gate blocks per group
#define PTJ 224     // pt row stride (14 j-tiles x 16)
#define PCJ 80      // partC per-(row,gb) f32 stride: 64 vt + u,d + pad
#define POJ 128     // partO per-(row,gb) f32 stride: ot cols

typedef __hip_bfloat16 bf16;
typedef __attribute__((ext_vector_type(8))) short short8;
typedef __attribute__((ext_vector_type(4))) float floatx4;

__device__ __forceinline__ float sigmoidf_(float v) { return 1.f / (1.f + expf(-v)); }
__device__ __forceinline__ float b2f(bf16 v) { return __bfloat162float(v); }
__device__ __forceinline__ float load_in(const void* p, size_t i, int isf32) {
    return isf32 ? ((const float*)p)[i] : b2f(((const bf16*)p)[i]);
}
__device__ __forceinline__ unsigned short f2bfbits(float v) {
    unsigned u = __builtin_bit_cast(unsigned, v);
    unsigned r = (u + 0x7FFFu + ((u >> 16) & 1u)) >> 16;
    return (unsigned short)r;
}
__device__ __forceinline__ float bfbits2f(unsigned short b) {
    return __builtin_bit_cast(float, (unsigned)b << 16);
}
__device__ __forceinline__ unsigned aload(const unsigned* p) {
    return __hip_atomic_load(p, __ATOMIC_RELAXED, __HIP_MEMORY_SCOPE_AGENT);
}
__device__ __forceinline__ unsigned long long aload64(const unsigned long long* p) {
    return __hip_atomic_load(p, __ATOMIC_RELAXED, __HIP_MEMORY_SCOPE_AGENT);
}
__device__ __forceinline__ void astore32(unsigned* p, unsigned v) {
    __hip_atomic_store(p, v, __ATOMIC_RELAXED, __HIP_MEMORY_SCOPE_AGENT);
}
__device__ __forceinline__ void astore64(unsigned long long* p, unsigned long long v) {
    __hip_atomic_store(p, v, __ATOMIC_RELAXED, __HIP_MEMORY_SCOPE_AGENT);
}
__device__ __forceinline__ unsigned long long packf2(float a, float b) {
    return (unsigned long long)__builtin_bit_cast(unsigned, a)
         | ((unsigned long long)__builtin_bit_cast(unsigned, b) << 32);
}
__device__ __forceinline__ void unpack_frag(const unsigned long long* ap,
                                            short8& ah, short8& al) {
    #pragma unroll
    for (int j = 0; j < 4; j++) {
        unsigned long long q = aload64(ap + j);
        unsigned u0 = (unsigned)q, u1 = (unsigned)(q >> 32);
        ah[2 * j]     = (short)(u0 & 0xffffu);
        al[2 * j]     = (short)(u0 >> 16);
        ah[2 * j + 1] = (short)(u1 & 0xffffu);
        al[2 * j + 1] = (short)(u1 >> 16);
    }
}

// Poll 16 consecutive epoch flags (stride-16 uints) until all >= tgt.
// Producers store flags AFTER a per-wave vmcnt drain of their data stores
// (+ __syncthreads across the block) -> flag >= tgt implies data visible.
__device__ __forceinline__ void wait_flags16(const unsigned* f, int base16,
                                             unsigned tgt) {
    if (threadIdx.x < 16) {
        while (aload(&f[(base16 + (int)threadIdx.x) * 16]) < tgt)
            __builtin_amdgcn_s_sleep(1);
    }
    __atomic_signal_fence(__ATOMIC_SEQ_CST);
    __syncthreads();
}

// dtype detect (defensive): f32 data has random low halves -> bf16-exp >= 0x8F
__global__ void detect_kernel(const unsigned short* __restrict__ w, int* __restrict__ flag) {
    if (threadIdx.x == 0) {
        int isf32 = 0;
        for (int i = 0; i < 256; i++) {
            int e = (w[i] >> 7) & 0xFF;
            if (e >= 0x8F) isf32 = 1;
        }
        *flag = isf32;
    }
}

// Gate-interleaved combined weights in B-fragment layout (hi/lo bf16 split).
__global__ void prep_kernel(const void* __restrict__ Wih, const void* __restrict__ bih,
                            const void* __restrict__ Whh, const void* __restrict__ bhh,
                            unsigned short* __restrict__ WfH, unsigned short* __restrict__ WfL,
                            float* __restrict__ bc, const int* __restrict__ flag) {
    int isf32 = *flag;
    int jp = blockIdx.x;
    int u = jp >> 2, gate = jp & 3;
    int src = gate * HDIM + u;
    int jt = jp >> 4, jn = jp & 15;
    for (int k = threadIdx.x; k < KTOT; k += blockDim.x) {
        float v = (k < 192) ? load_in(Wih, (size_t)src * 192 + k, isf32)
                            : load_in(Whh, (size_t)src * HDIM + (k - 192), isf32);
        unsigned short hi = f2bfbits(v);
        unsigned short lo = f2bfbits(v - bfbits2f(hi));
        int ks = k >> 5, q = (k & 31) >> 3, e = k & 7;
        size_t d = (((size_t)jt * 22 + ks) * 64 + (q * 16 + jn)) * 8 + e;
        WfH[d] = hi;
        WfL[d] = lo;
    }
    if (threadIdx.x == 0)
        bc[jp] = load_in(bih, src, isf32) + load_in(bhh, src, isf32);
}

// Wr -> row-major bf16 hi/lo (224 rows, rows >= 194 zero) + brf f32 (padded).
__global__ void wr_prep_kernel(const void* __restrict__ Wr, const void* __restrict__ br,
                               unsigned short* __restrict__ WrBh, unsigned short* __restrict__ WrBl,
                               float* __restrict__ brf, const int* __restrict__ flag) {
    int isf32 = *flag;
    int j = blockIdx.x;
    for (int k = threadIdx.x; k < HDIM; k += blockDim.x) {
        float v = (j < ROUT) ? load_in(Wr, (size_t)j * HDIM + k, isf32) : 0.f;
        unsigned short hi = f2bfbits(v);
        WrBh[(size_t)j * HDIM + k] = hi;
        WrBl[(size_t)j * HDIM + k] = f2bfbits(v - bfbits2f(hi));
    }
    if (threadIdx.x == 0) brf[j] = (j < ROUT) ? load_in(br, j, isf32) : 0.f;
}

// ---- persistent kernel (R20 = R19 + crit-first direct publish + P2 fast einsum) ----
// Differences from R19 (3075us, passing):
//   (a) crit readout (vt tile wv + u,d tile 12) runs FIRST after the epilogue
//       and publishes DIRECTLY from MFMA C registers to partC (no pt bounce,
//       one fewer sync); pfl is posted BEFORE the h publish -> rt-loop (the
//       longer pole) starts ~0.5-1us earlier. WAR proofs unchanged: pfl>=t+1
//       still implies gates finished step t's rt-frag read (crit publish
//       follows the rt-MFMA in program order).
//   (b) P2: when the sparse suffix is short (e0 > t-16, uniform branch),
//       wave 0 computes the einsum alone -- skips red[] round trip + 1 sync.
// Everything else (frag staging, gate MFMA, epilogue, h publish, ot parity
// path, P2 scan): R19 verbatim.
__global__ __launch_bounds__(256) void persist_kernel(
        const void* __restrict__ x,
        const unsigned short* __restrict__ WfH, const unsigned short* __restrict__ WfL,
        const float* __restrict__ bc,
        const unsigned short* __restrict__ WrBh, const unsigned short* __restrict__ WrBl,
        const float* __restrict__ brf,
        unsigned* __restrict__ AfP,          // 2 x AFRAG_U uints (hi | lo<<16)
        float* __restrict__ partC,           // [128 rows][16 gb][PCJ] f32 (vt,u,d)
        float* __restrict__ partO,           // [2][128 rows][16 gb][POJ] f32 (ot)
        unsigned short* __restrict__ Vg,     // [128][259][64] bf16, row-private
        void* __restrict__ dout, const int* __restrict__ flag,
        unsigned* __restrict__ hfl, unsigned* __restrict__ pfl,
        unsigned* __restrict__ rtf, unsigned* __restrict__ oflg) {
    __shared__ __align__(16) short Ahs[18 * 64 * 8];          // staged A hi; pt overlay
    __shared__ __align__(16) short Als[18 * 64 * 8];          // staged A lo
    __shared__ __align__(16) unsigned short wrslB[14 * 64 * 8];   // Wr hi, B-frag layout
    __shared__ __align__(16) unsigned short wrslBL[14 * 64 * 8];  // Wr lo, B-frag layout
    __shared__ __align__(16) float scr[8][16][20];
    __shared__ __align__(16) unsigned short hlh[16 * 40];     // h hi bf16 (pad 40)
    __shared__ __align__(16) unsigned short hll[16 * 40];     // h lo bf16
    __shared__ __align__(16) float outsC[80];                 // vt(64) + u,d
    __shared__ __align__(16) float sL[324];
    __shared__ __align__(16) float aL[324];
    __shared__ __align__(16) float red[4][64];
    __shared__ __align__(16) float redo[128][2];
    __shared__ __align__(16) float oL[128];
    __shared__ __align__(16) float brS[208];
    __shared__ __align__(16) float bcS[128];
    __shared__ int e0S;

    const int tid = threadIdx.x, lane = tid & 63, wv = tid >> 6;
    const int blk = blockIdx.x, ms = blk >> 5, ns = blk & 31;
    const int isf32 = *flag;
    float* const pt = (float*)Ahs;       // 16 x PTJ f32 overlay (14.3KB <= 18.4KB)

    const int is_gate = (ns < 16);
    const int gb = ns;                   // gate block index (when is_gate)
    const int pb = ns - 16;              // P2 index (when !is_gate)
    const int p2row = ms * 16 + pb;      // P2's batch row

    if (is_gate) {
        // Wr slice in B-frag layout: tile jt (14), lane l, elem e ->
        // row j = jt*16 + (l&15), col k = gb*32 + (l>>4)*8 + e.
        for (int i = tid; i < 14 * 64 * 8; i += 256) {
            int jt = i >> 9, l = (i >> 3) & 63, e = i & 7;
            size_t src = (size_t)(jt * 16 + (l & 15)) * HDIM + gb * 32 + (l >> 4) * 8 + e;
            wrslB[i]  = WrBh[src];
            wrslBL[i] = WrBl[src];
        }
        if (tid < 128) bcS[tid] = bc[gb * 128 + tid];
    } else {
        for (int i = tid; i < 208; i += 256) brS[i] = brf[i];
        for (int i = tid; i < 324; i += 256) { sL[i] = 0.f; aL[i] = 0.f; }
    }
    __syncthreads();

    if (is_gate) {
        // =========================== GATE BLOCK ===========================
        const short8* WH = (const short8*)WfH;
        const short8* WL = (const short8*)WfL;
        const int jt0 = gb * 8 + wv, jt1 = gb * 8 + 4 + wv;
        const short8* wb0  = WH + (size_t)jt0 * 22 * 64;
        const short8* wb1  = WH + (size_t)jt1 * 22 * 64;
        const short8* wbl0 = WL + (size_t)jt0 * 22 * 64;
        const short8* wbl1 = WL + (size_t)jt1 * 22 * 64;
        float cc0 = 0.f, cc1 = 0.f;

        for (int t = 0; t < MAXT; t++) {
            const int cur = t & 1, nxt = cur ^ 1;
            const unsigned long long* AfPc64 =
                (const unsigned long long*)(AfP + (size_t)cur * AFRAG_U);
            unsigned long long* AfPn64 =
                (unsigned long long*)(AfP + (size_t)nxt * AFRAG_U);
            const int use_x = (t < 129);

            // P1-x: x MFMAs BEFORE the h wait (independent of h(t-1))
            floatx4 acc0 = {0.f, 0.f, 0.f, 0.f};
            floatx4 acc1 = {0.f, 0.f, 0.f, 0.f};
            if (use_x) {
                int m = lane & 15, q = lane >> 4;
                size_t xrow = ((size_t)t * BATCH + ms * 16 + m) * IDIM + q * 8;
                #pragma unroll
                for (int ks = 0; ks < 4; ks++) {
                    short8 a;
                    if (isf32) {
                        const float* xf = (const float*)x + xrow + ks * 32;
                        #pragma unroll
                        for (int i = 0; i < 8; i++) a[i] = (short)f2bfbits(xf[i]);
                    } else {
                        a = *(const short8*)((const unsigned short*)x + xrow + ks * 32);
                    }
                    acc0 = __builtin_amdgcn_mfma_f32_16x16x32_bf16(a, wb0[ks * 64 + lane], acc0, 0, 0, 0);
                    acc1 = __builtin_amdgcn_mfma_f32_16x16x32_bf16(a, wb1[ks * 64 + lane], acc1, 0, 0, 0);
                    if (isf32) {
                        acc0 = __builtin_amdgcn_mfma_f32_16x16x32_bf16(a, wbl0[ks * 64 + lane], acc0, 0, 0, 0);
                        acc1 = __builtin_amdgcn_mfma_f32_16x16x32_bf16(a, wbl1[ks * 64 + lane], acc1, 0, 0, 0);
                    }
                }
            }

            // wait h(t-1) frags from all 16 gate blocks, then stage to LDS (R15)
            wait_flags16(hfl, ms * 16, (unsigned)t);
            #pragma unroll
            for (int i0 = 0; i0 < 4; i0++) {
                int i = i0 * 256 + tid;
                int ksi = 2 + (i >> 6), l = i & 63;
                const unsigned long long* ap =
                    AfPc64 + ((size_t)(ms * 18 + ksi) * 64 + l) * 4;
                short8 ah, al8;
                unpack_frag(ap, ah, al8);
                *(short8*)&Ahs[(ksi * 64 + l) * 8] = ah;
                *(short8*)&Als[(ksi * 64 + l) * 8] = al8;
            }
            __syncthreads();

            // h MFMAs (ksi 2..17) from LDS (R15 verbatim)
            #pragma unroll 4
            for (int ksi = 2; ksi < 18; ksi++) {
                int ks = 4 + ksi;
                short8 ah  = *(const short8*)&Ahs[(ksi * 64 + lane) * 8];
                short8 al8 = *(const short8*)&Als[(ksi * 64 + lane) * 8];
                short8 bh0 = wb0[ks * 64 + lane];
                short8 bh1 = wb1[ks * 64 + lane];
                acc0 = __builtin_amdgcn_mfma_f32_16x16x32_bf16(ah, bh0, acc0, 0, 0, 0);
                acc0 = __builtin_amdgcn_mfma_f32_16x16x32_bf16(al8, bh0, acc0, 0, 0, 0);
                acc1 = __builtin_amdgcn_mfma_f32_16x16x32_bf16(ah, bh1, acc1, 0, 0, 0);
                acc1 = __builtin_amdgcn_mfma_f32_16x16x32_bf16(al8, bh1, acc1, 0, 0, 0);
                if (isf32) {
                    acc0 = __builtin_amdgcn_mfma_f32_16x16x32_bf16(ah, wbl0[ks * 64 + lane], acc0, 0, 0, 0);
                    acc1 = __builtin_amdgcn_mfma_f32_16x16x32_bf16(ah, wbl1[ks * 64 + lane], acc1, 0, 0, 0);
                }
            }

            // wait rt(t-1); stage rt frags (ksi 0..1); finish gates (R15)
            wait_flags16(rtf, ms * 16, (unsigned)t);
            if (tid < 128) {
                int ksi = tid >> 6, l = tid & 63;
                const unsigned long long* ap =
                    AfPc64 + ((size_t)(ms * 18 + ksi) * 64 + l) * 4;
                short8 ah, al8;
                unpack_frag(ap, ah, al8);
                *(short8*)&Ahs[(ksi * 64 + l) * 8] = ah;
                *(short8*)&Als[(ksi * 64 + l) * 8] = al8;
            }
            __syncthreads();
            #pragma unroll
            for (int ksi = 0; ksi < 2; ksi++) {
                int ks = 4 + ksi;
                short8 ah  = *(const short8*)&Ahs[(ksi * 64 + lane) * 8];
                short8 al8 = *(const short8*)&Als[(ksi * 64 + lane) * 8];
                short8 bh0 = wb0[ks * 64 + lane];
                short8 bh1 = wb1[ks * 64 + lane];
                acc0 = __builtin_amdgcn_mfma_f32_16x16x32_bf16(ah, bh0, acc0, 0, 0, 0);
                acc0 = __builtin_amdgcn_mfma_f32_16x16x32_bf16(al8, bh0, acc0, 0, 0, 0);
                acc1 = __builtin_amdgcn_mfma_f32_16x16x32_bf16(ah, bh1, acc1, 0, 0, 0);
                acc1 = __builtin_amdgcn_mfma_f32_16x16x32_bf16(al8, bh1, acc1, 0, 0, 0);
                if (isf32) {
                    acc0 = __builtin_amdgcn_mfma_f32_16x16x32_bf16(ah, wbl0[ks * 64 + lane], acc0, 0, 0, 0);
                    acc1 = __builtin_amdgcn_mfma_f32_16x16x32_bf16(ah, wbl1[ks * 64 + lane], acc1, 0, 0, 0);
                }
            }
            {
                int n = lane & 15, m0 = (lane >> 4) * 4;
                #pragma unroll
                for (int r = 0; r < 4; r++) scr[wv][m0 + r][n] = acc0[r];
                #pragma unroll
                for (int r = 0; r < 4; r++) scr[wv + 4][m0 + r][n] = acc1[r];
            }
            __syncthreads();
            // cell epilogue (R15 verbatim)
            {
                int r = tid >> 4, p = tid & 15;
                float4 g = *(const float4*)&scr[p >> 2][r][(p & 3) * 4];
                float4 bb = *(const float4*)&bcS[p * 4];
                float c2 = sigmoidf_(g.y + bb.y) * cc0 + sigmoidf_(g.x + bb.x) * tanhf(g.z + bb.z);
                float h2 = sigmoidf_(g.w + bb.w) * tanhf(c2);
                cc0 = c2;
                unsigned short hi0 = f2bfbits(h2);
                hlh[r * 40 + p] = hi0;
                hll[r * 40 + p] = f2bfbits(h2 - bfbits2f(hi0));
                int u1 = p + 16;
                float4 g1 = *(const float4*)&scr[u1 >> 2][r][(u1 & 3) * 4];
                float4 bb1 = *(const float4*)&bcS[u1 * 4];
                float c21 = sigmoidf_(g1.y + bb1.y) * cc1 + sigmoidf_(g1.x + bb1.x) * tanhf(g1.z + bb1.z);
                float h21 = sigmoidf_(g1.w + bb1.w) * tanhf(c21);
                cc1 = c21;
                unsigned short hi1 = f2bfbits(h21);
                hlh[r * 40 + u1] = hi1;
                hll[r * 40 + u1] = f2bfbits(h21 - bfbits2f(hi1));
            }
            __syncthreads();   // hlh/hll ready; Ahs dead -> pt overlay OK (ot path)

            // --- crit readout FIRST (rt-loop priority): tile wv (+12 on wv0),
            // publish DIRECTLY from C registers to partC; then pfl. ---
            {
                int m = lane & 15, q = lane >> 4;
                short8 ahh = *(const short8*)&hlh[m * 40 + q * 8];
                short8 ahl = *(const short8*)&hll[m * 40 + q * 8];
                int n = lane & 15, m0 = (lane >> 4) * 4;
                // tile wv -> vt cols wv*16 + n for all 16 rows
                {
                    const short8* bB  = (const short8*)&wrslB[((size_t)wv * 64 + lane) * 8];
                    const short8* bBl = (const short8*)&wrslBL[((size_t)wv * 64 + lane) * 8];
                    floatx4 accR = {0.f, 0.f, 0.f, 0.f};
                    short8 bh = *bB;
                    accR = __builtin_amdgcn_mfma_f32_16x16x32_bf16(ahh, bh, accR, 0, 0, 0);
                    accR = __builtin_amdgcn_mfma_f32_16x16x32_bf16(ahl, bh, accR, 0, 0, 0);
                    if (isf32) {
                        short8 bl = *bBl;
                        accR = __builtin_amdgcn_mfma_f32_16x16x32_bf16(ahh, bl, accR, 0, 0, 0);
                        accR = __builtin_amdgcn_mfma_f32_16x16x32_bf16(ahl, bl, accR, 0, 0, 0);
                    }
                    #pragma unroll
                    for (int r = 0; r < 4; r++) {
                        int row = ms * 16 + m0 + r;
                        astore32((unsigned*)partC + ((size_t)row * NGATE + gb) * PCJ
                                     + wv * 16 + n,
                                 __builtin_bit_cast(unsigned, accR[r]));
                    }
                }
                if (wv == 0) {   // tile 12 -> u,d (j 192,193 -> slots 64,65)
                    const short8* bB  = (const short8*)&wrslB[((size_t)12 * 64 + lane) * 8];
                    const short8* bBl = (const short8*)&wrslBL[((size_t)12 * 64 + lane) * 8];
                    floatx4 accR = {0.f, 0.f, 0.f, 0.f};
                    short8 bh = *bB;
                    accR = __builtin_amdgcn_mfma_f32_16x16x32_bf16(ahh, bh, accR, 0, 0, 0);
                    accR = __builtin_amdgcn_mfma_f32_16x16x32_bf16(ahl, bh, accR, 0, 0, 0);
                    if (isf32) {
                        short8 bl = *bBl;
                        accR = __builtin_amdgcn_mfma_f32_16x16x32_bf16(ahh, bl, accR, 0, 0, 0);
                        accR = __builtin_amdgcn_mfma_f32_16x16x32_bf16(ahl, bl, accR, 0, 0, 0);
                    }
                    if (n < 2) {
                        #pragma unroll
                        for (int r = 0; r < 4; r++) {
                            int row = ms * 16 + m0 + r;
                            astore32((unsigned*)partC + ((size_t)row * NGATE + gb) * PCJ
                                         + 64 + n,
                                     __builtin_bit_cast(unsigned, accR[r]));
                        }
                    }
                }
            }
            asm volatile("s_waitcnt vmcnt(0)" ::: "memory");
            __syncthreads();
            if (tid == 0)
                __hip_atomic_store(&pfl[(ms * 16 + gb) * 16], (unsigned)(t + 1),
                                   __ATOMIC_RELAXED, __HIP_MEMORY_SCOPE_AGENT);

            // h publish (R15 verbatim) + hfl
            {
                int rr = tid >> 4, pp = tid & 15;
                unsigned short hb0 = hlh[rr * 40 + 2 * pp];
                unsigned short lb0 = hll[rr * 40 + 2 * pp];
                unsigned short hb1 = hlh[rr * 40 + 2 * pp + 1];
                unsigned short lb1 = hll[rr * 40 + 2 * pp + 1];
                unsigned u0 = (unsigned)hb0 | ((unsigned)lb0 << 16);
                unsigned u1 = (unsigned)hb1 | ((unsigned)lb1 << 16);
                int u_g = gb * 32 + 2 * pp;
                int ksi2 = 2 + (u_g >> 5), q = (u_g & 31) >> 3, e = u_g & 7;
                size_t fi = (((size_t)ms * 18 + ksi2) * 64 + q * 16 + rr) * 8 + e;
                astore64(AfPn64 + fi / 2, (unsigned long long)u0 | ((unsigned long long)u1 << 32));
            }
            asm volatile("s_waitcnt vmcnt(0)" ::: "memory");
            __syncthreads();
            if (tid == 0)
                __hip_atomic_store(&hfl[(ms * 16 + gb) * 16], (unsigned)(t + 1),
                                   __ATOMIC_RELAXED, __HIP_MEMORY_SCOPE_AGENT);

            // ot readout + publish, ONLY t>=129 (parity buffer; off crit loop)
            if (!use_x) {
                {
                    int m = lane & 15, q = lane >> 4;
                    short8 ahh = *(const short8*)&hlh[m * 40 + q * 8];
                    short8 ahl = *(const short8*)&hll[m * 40 + q * 8];
                    int n = lane & 15, m0 = (lane >> 4) * 4;
                    #pragma unroll
                    for (int s2 = 0; s2 < 2; s2++) {
                        int jt = 4 + wv + s2 * 4;
                        const short8* bB  = (const short8*)&wrslB[((size_t)jt * 64 + lane) * 8];
                        const short8* bBl = (const short8*)&wrslBL[((size_t)jt * 64 + lane) * 8];
                        floatx4 accR = {0.f, 0.f, 0.f, 0.f};
                        short8 bh = *bB;
                        accR = __builtin_amdgcn_mfma_f32_16x16x32_bf16(ahh, bh, accR, 0, 0, 0);
                        accR = __builtin_amdgcn_mfma_f32_16x16x32_bf16(ahl, bh, accR, 0, 0, 0);
                        if (isf32) {
                            short8 bl = *bBl;
                            accR = __builtin_amdgcn_mfma_f32_16x16x32_bf16(ahh, bl, accR, 0, 0, 0);
                            accR = __builtin_amdgcn_mfma_f32_16x16x32_bf16(ahl, bl, accR, 0, 0, 0);
                        }
                        #pragma unroll
                        for (int ri = 0; ri < 4; ri++)
                            pt[(m0 + ri) * PTJ + jt * 16 + n] = accR[ri];
                    }
                }
                __syncthreads();
                {
                    #pragma unroll
                    for (int it = 0; it < 4; it++) {
                        int rloc = wv * 4 + it;
                        int prow_ = ms * 16 + rloc;
                        const float* pr = pt + rloc * PTJ;
                        unsigned long long* pb64 = (unsigned long long*)
                            (partO + ((((size_t)cur * BATCH + prow_) * NGATE) + gb) * POJ);
                        astore64(pb64 + lane, packf2(pr[64 + 2 * lane], pr[65 + 2 * lane]));
                    }
                }
                asm volatile("s_waitcnt vmcnt(0)" ::: "memory");
                __syncthreads();
                if (tid == 0)
                    __hip_atomic_store(&oflg[(ms * 16 + gb) * 16], (unsigned)(t + 1),
                                       __ATOMIC_RELAXED, __HIP_MEMORY_SCOPE_AGENT);
            }
        }
    } else {
        // ============================ P2 BLOCK ============================
        unsigned short* Vrow = Vg + (size_t)p2row * MAXT * SDIM;
        for (int t = 0; t < MAXT; t++) {
            unsigned long long* AfPn64 =
                (unsigned long long*)(AfP + (size_t)((t + 1) & 1) * AFRAG_U);

            // wait crit partials(t) from all 16 gate blocks of this group
            wait_flags16(pfl, ms * 16, (unsigned)(t + 1));

            if (tid < 66) {
                const unsigned* pb2 = (const unsigned*)partC
                                    + (size_t)p2row * NGATE * PCJ + tid;
                float s4 = (tid < 64) ? brS[tid] : brS[128 + tid];  // 64->192, 65->193
                #pragma unroll
                for (int g = 0; g < NGATE; g++)
                    s4 += __builtin_bit_cast(float, aload(pb2 + (size_t)g * PCJ));
                outsC[tid] = s4;
            }
            __syncthreads();
            if (wv == 0) {
                float uval = sigmoidf_(outsC[64]);
                float dval = sigmoidf_(outsC[65]);
                Vrow[t * SDIM + lane] = f2bfbits(outsC[lane]);
                int ebase = lane * 5;
                float sv[5], suf[5];
                #pragma unroll
                for (int j = 0; j < 5; j++) {
                    int e = ebase + j;
                    sv[j] = (e < MAXT) ? sL[e] : 0.f;
                }
                suf[4] = sv[4];
                #pragma unroll
                for (int j = 3; j >= 0; j--) suf[j] = sv[j] + suf[j + 1];
                float ltot = suf[0];
                float accs = ltot;
                #pragma unroll
                for (int off = 1; off < 64; off <<= 1) {
                    float y = __shfl_down(accs, off, 64);
                    if (lane + off < 64) accs += y;
                }
                float after_lane = accs - ltot;
                int emin = 0x7fffffff;
                #pragma unroll
                for (int j = 0; j < 5; j++) {
                    int e = ebase + j;
                    if (e <= t) {
                        float prod = after_lane + (suf[j] - sv[j]);
                        float sp = (e == t) ? dval
                                            : fmaxf(0.f, sv[j] - fmaxf(0.f, uval - prod));
                        float inner = fmaxf(0.f, 1.f - prod - sp);
                        sL[e] = sp;
                        aL[e] = fminf(sp, inner);
                        // A[e] nonzero only where prod < 1 (monotone suffix)
                        if (prod < 1.f && e < emin) emin = e;
                    }
                }
                #pragma unroll
                for (int off = 32; off; off >>= 1) {
                    int o = __shfl_xor(emin, off, 64);
                    emin = o < emin ? o : emin;
                }
                if (lane == 0) e0S = emin;
            }
            __syncthreads();
            // einsum over sparse suffix: single-wave fast path when short.
            // Branch is uniform (e0S shared, t uniform) -> conditional
            // __syncthreads below is legal.
            const int e0 = e0S;
            float rtv = 0.f;
            if (e0 > t - 16) {
                if (wv == 0) {
                    for (int i2 = e0; i2 <= t; i2++)
                        rtv += aL[i2] * bfbits2f(Vrow[i2 * SDIM + lane]);
                }
            } else {
                float racc = 0.f;
                int i2s = e0 + ((wv - e0) & 3);
                for (int i2 = i2s; i2 <= t; i2 += 4)
                    racc += aL[i2] * bfbits2f(Vrow[i2 * SDIM + lane]);
                red[wv][lane] = racc;
                __syncthreads();
                if (wv == 0)
                    rtv = red[0][lane] + red[1][lane] + red[2][lane] + red[3][lane];
            }
            if (wv == 0) {
                float rtn = __shfl_down(rtv, 1, 64);
                if ((lane & 1) == 0) {
                    unsigned short hb0 = f2bfbits(rtv);
                    unsigned short lb0 = f2bfbits(rtv - bfbits2f(hb0));
                    unsigned short hb1 = f2bfbits(rtn);
                    unsigned short lb1 = f2bfbits(rtn - bfbits2f(hb1));
                    unsigned u0 = (unsigned)hb0 | ((unsigned)lb0 << 16);
                    unsigned u1 = (unsigned)hb1 | ((unsigned)lb1 << 16);
                    int d0 = lane;
                    int ksi = d0 >> 5, q = (d0 & 31) >> 3, e = d0 & 7;
                    size_t fi = (((size_t)ms * 18 + ksi) * 64 + q * 16 + pb) * 8 + e;
                    astore64(AfPn64 + fi / 2,
                             (unsigned long long)u0 | ((unsigned long long)u1 << 32));
                }
                asm volatile("s_waitcnt vmcnt(0)" ::: "memory");
                if (lane == 0)
                    __hip_atomic_store(&rtf[(ms * 16 + pb) * 16], (unsigned)(t + 1),
                                       __ATOMIC_RELAXED, __HIP_MEMORY_SCOPE_AGENT);
            }
            // output path (t >= 129): wait ot partials, reduce, log-softmax.
            // Safe vs WAR by partO parity (see R19 proof).
            if (t >= 129) {
                wait_flags16(oflg, ms * 16, (unsigned)(t + 1));
                {
                    int col = tid >> 1, half = tid & 1;
                    const unsigned* pbo = (const unsigned*)partO
                        + (((size_t)(t & 1) * BATCH + p2row) * NGATE) * POJ + col;
                    float s = 0.f;
                    #pragma unroll
                    for (int g = 0; g < 8; g++)
                        s += __builtin_bit_cast(float,
                                aload(pbo + (size_t)(half * 8 + g) * POJ));
                    redo[col][half] = s;
                }
                __syncthreads();
                if (tid < 128) oL[tid] = redo[tid][0] + redo[tid][1] + brS[64 + tid];
                __syncthreads();
                if (wv == 0) {
                    float a = oL[lane];
                    float bvv = oL[64 + lane];
                    float m = fmaxf(a, bvv);
                    #pragma unroll
                    for (int off = 32; off; off >>= 1) m = fmaxf(m, __shfl_xor(m, off, 64));
                    float e = expf(a - m) + expf(bvv - m);
                    #pragma unroll
                    for (int off = 32; off; off >>= 1) e += __shfl_xor(e, off, 64);
                    float ls = logf(e) + m;
                    size_t base = ((size_t)(t - 129) * BATCH + p2row) * IDIM;
                    if (isf32) {
                        ((float*)dout)[base + lane] = a - ls;
                        ((float*)dout)[base + lane + 64] = bvv - ls;
                    } else {
                        ((bf16*)dout)[base + lane] = __float2bfloat16(a - ls);
                        ((bf16*)dout)[base + lane + 64] = __float2bfloat16(bvv - ls);
                    }
                }
            }
        }
    }
}

extern "C" void kernel_launch(void* const* d_in, const int* in_sizes, int n_in,
                              void* d_out, int out_size, void* d_ws, size_t ws_size,
                              hipStream_t stream) {
    const void* x   = d_in[0];
    const void* Wih = d_in[1];
    const void* bih = d_in[2];
    const void* Whh = d_in[3];
    const void* bhh = d_in[4];
    const void* Wr  = d_in[5];
    const void* br  = d_in[6];

    char* base = (char*)d_ws;
    size_t off = 0;
    int* flag = (int*)base;                                   off += 64;
    unsigned* hfl = (unsigned*)(base + off);                  off += 128 * 64 + 64;
    unsigned* pfl = (unsigned*)(base + off);                  off += 128 * 64 + 64;
    unsigned* rtf = (unsigned*)(base + off);                  off += 128 * 64 + 64;
    unsigned* oflg = (unsigned*)(base + off);                 off += 128 * 64 + 64;
    unsigned short* WfH  = (unsigned short*)(base + off);     off += (size_t)G4 * KTOT * 2;
    unsigned short* WfL  = (unsigned short*)(base + off);     off += (size_t)G4 * KTOT * 2;
    unsigned short* WrBh = (unsigned short*)(base + off);     off += (size_t)224 * HDIM * 2;
    unsigned short* WrBl = (unsigned short*)(base + off);     off += (size_t)224 * HDIM * 2;
    float* bc   = (float*)(base + off);                       off += G4 * 4;
    float* brf  = (float*)(base + off);                       off += 1024;
    unsigned* AfP = (unsigned*)(base + off);                  size_t af_off = off;
                                                              off += (size_t)2 * AFRAG_U * 4;
    float* partC = (float*)(base + off);                      off += (size_t)BATCH * NGATE * PCJ * 4;
    float* partO = (float*)(base + off);                      off += (size_t)2 * BATCH * NGATE * POJ * 4;
    unsigned short* Vg = (unsigned short*)(base + off);       off += (size_t)BATCH * MAXT * SDIM * 2;
    // total ~14 MB

    hipMemsetAsync(base + 64, 0, 4 * (128 * 64 + 64), stream);         // hfl/pfl/rtf/oflg
    hipMemsetAsync(base + af_off, 0, (size_t)2 * AFRAG_U * 4, stream); // A-frag buffers
    hipMemsetAsync(partC, 0, (size_t)BATCH * NGATE * PCJ * 4, stream); // stale-read hygiene

    detect_kernel<<<1, 64, 0, stream>>>((const unsigned short*)Wih, flag);
    prep_kernel<<<G4, 256, 0, stream>>>(Wih, bih, Whh, bhh, WfH, WfL, bc, flag);
    wr_prep_kernel<<<224, 256, 0, stream>>>(Wr, br, WrBh, WrBl, brf, flag);

    persist_kernel<<<NBLK, 256, 0, stream>>>(x, WfH, WfL, bc, WrBh, WrBl, brf,
                                             AfP, partC, partO, Vg, d_out, flag,
                                             hfl, pfl, rtf, oflg);

    (void)in_sizes; (void)n_in; (void)out_size; (void)ws_size;
}